// Round 1
// baseline (165.614 us; speedup 1.0000x reference)
//
#include <hip/hip_runtime.h>
#include <hip/hip_bf16.h>

#define B_    4
#define S_    2048
#define HID_  768
#define H_    12
#define DBLK_ 256
#define HD_   64
#define BH_   (B_ * H_)                 // 48
#define QSZ_  (B_ * H_ * S_ * HD_)      // 6291456 elements
#define WTSZ_ (3 * H_ * HD_ * DBLK_)    // 589824 elements

typedef _Float16 f16x4 __attribute__((ext_vector_type(4)));
typedef _Float16 f16x8 __attribute__((ext_vector_type(8)));
typedef float    f32x4 __attribute__((ext_vector_type(4)));
typedef float    f32x16 __attribute__((ext_vector_type(16)));

#if __has_builtin(__builtin_amdgcn_exp2f)
#define EXP2(x) __builtin_amdgcn_exp2f(x)
#else
#define EXP2(x) exp2f(x)
#endif

typedef const void __attribute__((address_space(1)))* gptr_t;
typedef       void __attribute__((address_space(3)))* sptr_t;

// ---------------------------------------------------------------------------
// Kernel 0: W fp32 -> f16 in exact MFMA B-fragment order (unchanged).
// ---------------------------------------------------------------------------
__global__ __launch_bounds__(256) void wconv(
    const float* __restrict__ Wq, const float* __restrict__ Wk,
    const float* __restrict__ Wv, _Float16* __restrict__ whf)
{
    const int idx  = blockIdx.x * 256 + threadIdx.x;
    const int j    = idx & 7;
    const int lane = (idx >> 3) & 63;
    const int et   = (idx >> 9) & 1;
    const int kk   = (idx >> 10) & 7;
    const int eh   = (idx >> 13) & 1;
    const int ph   = idx >> 14;          // p*12 + h
    const int h    = ph % H_;
    const int p    = ph / H_;
    const int e = eh * 32 + et * 16 + (lane & 15);
    const int k = kk * 32 + (lane >> 4) * 8 + j;
    const float* W = (p == 0) ? Wq : (p == 1) ? Wk : Wv;
    whf[idx] = (_Float16)W[((size_t)h * DBLK_ + k) * HD_ + e];
}

// ---------------------------------------------------------------------------
// Kernel 1: block-diagonal QKV projection.
// MFMA phase unchanged. Epilogue as before EXCEPT the K-row permutation:
//  - K tile rows now stored with token sl at row swap(bit2,bit3)(sl).
//    With 32x32x16 swapped-QK in attn, C-reg (mt,reg) at lane-group g holds
//    the score of LDS row mt*32+(reg&3)+8*(reg>>2)+4g; packing reg
//    (ks&1)*8+j of c[ks>>1] into PV A-slot (ks,g,j) then contracts against
//    V^T column ks*16+8g+j -- the bit2/bit3 swap makes token==column.
//  - K/V tiles chunk-XOR-swizzled exactly as before (key = row&7).
// ---------------------------------------------------------------------------
__global__ __launch_bounds__(256, 3) void qkv_proj(
    const float* __restrict__ x, const _Float16* __restrict__ whf,
    const float* __restrict__ bq, const float* __restrict__ bk,
    const float* __restrict__ bv,
    _Float16* __restrict__ qo, _Float16* __restrict__ khf,
    _Float16* __restrict__ vtf)
{
    const int i   = blockIdx.x;          // g*128 + sc
    const int g   = i >> 7;              // 0..5
    const int sc  = i & 127;
    const int m   = g >> 1;
    const int s0g = sc * 64;

    const int tid  = threadIdx.x;
    const int lane = tid & 63;
    const int w    = tid >> 6;
    const int ln   = lane & 15;
    const int qd   = lane >> 4;
    const int h    = 2 * g + (w >> 1);
    const int eh   = w & 1;

    __shared__ _Float16 xs[64 * 256];    // 32 KB, reused by the epilogue

    {   // stage X: 64 rows x 256 cols, fp32 -> f16, 16B-granule XOR swizzle
        const int rr   = tid >> 6;
        const int c4   = tid & 63;
        const int g16  = c4 >> 1;
        const int half = c4 & 1;
        #pragma unroll
        for (int pass = 0; pass < 16; pass++) {
            const int r = pass * 4 + rr;
            const float4 v = *(const float4*)(
                x + (size_t)(s0g + r) * HID_ + m * DBLK_ + c4 * 4);
            f16x4 hv;
            hv[0] = (_Float16)v.x; hv[1] = (_Float16)v.y;
            hv[2] = (_Float16)v.z; hv[3] = (_Float16)v.w;
            *(f16x4*)(xs + r * 256 + ((g16 ^ (r & 7)) * 8) + half * 4) = hv;
        }
    }
    __syncthreads();

    f32x4 acc[3][2][4];                  // [p][et][strip]
    #pragma unroll
    for (int p = 0; p < 3; p++)
        #pragma unroll
        for (int et = 0; et < 2; et++)
            #pragma unroll
            for (int st = 0; st < 4; st++)
                acc[p][et][st] = (f32x4){0.f, 0.f, 0.f, 0.f};

    const _Float16* wb = whf + (size_t)((h * 2 + eh) * 16) * 512 + lane * 8;

    for (int kk = 0; kk < 8; kk++) {
        f16x8 a[4];
        #pragma unroll
        for (int st = 0; st < 4; st++)
            a[st] = *(const f16x8*)(
                xs + (st * 16 + ln) * 256 + (((kk * 4 + qd) ^ (ln & 7)) * 8));
        #pragma unroll
        for (int p = 0; p < 3; p++)
            #pragma unroll
            for (int et = 0; et < 2; et++) {
                const f16x8 bb = *(const f16x8*)(
                    wb + (size_t)p * 196608 + (kk * 2 + et) * 512);
                #pragma unroll
                for (int st = 0; st < 4; st++)
                    acc[p][et][st] = __builtin_amdgcn_mfma_f32_16x16x32_f16(
                        a[st], bb, acc[p][et][st], 0, 0, 0);
            }
    }

    const float QS = 0.18033688011112042f;   // 0.125 * log2(e)
    const int b    = s0g >> 11;
    const int s0   = s0g & 2047;
    const int bhh  = b * H_ + h;
    const int tile = s0 >> 6;
    const int ht   = w >> 1;

    __syncthreads();                      // xs MFMA reads done; reuse as Q/K tiles
    // xs layout: Q tiles [ht][64 rows][8 chunks], K tiles at +8192 elems.
    // Both stored with chunk pos = c ^ (row&7). K rows bit2<->bit3 swapped.
    {
        _Float16* qtile = xs + ht * 4096;
        _Float16* ktile = xs + 8192 + ht * 4096;
        const size_t tbv = (size_t)(bhh * 32 + tile) * 4096;
        #pragma unroll
        for (int et = 0; et < 2; et++) {
            const int d  = eh * 32 + et * 16 + ln;
            const int dc = d >> 3, d7 = d & 7;
            const float biasq = bq[h * HD_ + d];
            const float biask = bk[h * HD_ + d];
            const float biasv = bv[h * HD_ + d];
            #pragma unroll
            for (int st = 0; st < 4; st++) {
                // V: direct global store, f16x4, swizzled V^T tile [d][kv]
                f16x4 vv;
                #pragma unroll
                for (int r = 0; r < 4; r++) vv[r] = (_Float16)(acc[2][et][st][r] + biasv);
                const int vc = st * 2 + (qd >> 1);
                *(f16x4*)(vtf + tbv + d * 64 + ((vc ^ d7) * 8) + (qd & 1) * 4) = vv;
                // Q/K into LDS (transpose staging)
                #pragma unroll
                for (int r = 0; r < 4; r++) {
                    const int sl  = st * 16 + qd * 4 + r;
                    // token sl = st*16 + qd*4 + r; row = swap(bit2,bit3)(sl)
                    const int rho = st * 16 + (qd & 1) * 8 + (qd >> 1) * 4 + r;
                    qtile[sl  * 64 + ((dc ^ (sl  & 7)) * 8) + d7] =
                        (_Float16)((acc[0][et][st][r] + biasq) * QS);
                    ktile[rho * 64 + ((dc ^ (rho & 7)) * 8) + d7] =
                        (_Float16)(acc[1][et][st][r] + biask);
                }
            }
        }
    }
    __syncthreads();
    // copy-out: 4 b128 Q + 4 b128 K per thread, fully coalesced global stores
    #pragma unroll
    for (int it = 0; it < 4; it++) {
        const int idx  = it * 256 + tid;      // 0..1023
        const int ht2  = idx >> 9;
        const int rest = idx & 511;
        const int row  = rest >> 3;
        const int c    = rest & 7;
        const int bhh2 = b * H_ + 2 * g + ht2;
        // Q: unswizzle (read pos c^(row&7), write chunk c), natural row order
        const f16x8 qv = *(const f16x8*)(xs + ht2 * 4096 + row * 64 + ((c ^ (row & 7)) * 8));
        *(f16x8*)(qo + ((size_t)bhh2 * S_ + s0 + row) * HD_ + c * 8) = qv;
        // K: swizzle is part of the global tile layout -> linear copy
        const f16x8 kv8 = *(const f16x8*)(xs + 8192 + ht2 * 4096 + row * 64 + c * 8);
        *(f16x8*)(khf + (size_t)(bhh2 * 32 + tile) * 4096 + row * 64 + c * 8) = kv8;
    }
}

// ---------------------------------------------------------------------------
// Kernel 2: flash attention, q-split (128 q/block, 32 q/wave), kv tiles of 64.
// Rebuilt on 32x32x16 MFMA:
//  - QK^T swapped (A=K, B=Q): C col = lane&31 = q, which is exactly the PV
//    A-frag row -> exp2 packs register-local, no shuffles.
//  - 16 MFMA/iter (8 QK + 8 PV) replaces 36 of 16x16x32 (11% faster/FLOP,
//    l-accumulator moved off the MFMA pipe to 32 v_add_f32/iter).
//  - K rows bit2<->bit3 swapped in the global tile so A k-slots match V^T
//    columns read linearly. Same chunk-XOR swizzle, same DMA double-buffer.
// ---------------------------------------------------------------------------
__global__ __launch_bounds__(256, 3) void attn(
    const _Float16* __restrict__ qh, const _Float16* __restrict__ khf,
    const _Float16* __restrict__ vtf, float* __restrict__ out)
{
    const int i    = blockIdx.x;          // 0..767
    const int slot = i >> 3;
    const int bh   = (i & 7) * 6 + (slot % 6);   // XCD-banded bh
    const int qt   = slot / 6;            // 0..15
    const int h = bh % H_, b = bh / H_;
    const int q0 = qt * 128;

    const int tid  = threadIdx.x;
    const int lane = tid & 63;
    const int w    = tid >> 6;
    const int l5   = lane & 31;           // q-col / kv-row / d-row index
    const int g    = lane >> 5;           // k-slot group
    const int x7   = l5 & 7;              // chunk-XOR key

    __shared__ __align__(16) char lds[2][16384];   // [buf][ K 8KB | V 8KB ]

    // Q B-frags (pre-scaled by 0.125*log2e): lane holds q = l5, k = kk*16+8g+j
    f16x8 qf[4];
    {
        const _Float16* qb = qh + ((size_t)bh * S_ + q0 + w * 32 + l5) * HD_;
        #pragma unroll
        for (int kk = 0; kk < 4; kk++)
            qf[kk] = *(const f16x8*)(qb + kk * 16 + g * 8);
    }

    f32x16 o[2];
    #pragma unroll
    for (int dt = 0; dt < 2; dt++)
        #pragma unroll
        for (int r = 0; r < 16; r++) o[dt][r] = 0.f;
    float lp[4] = {0.f, 0.f, 0.f, 0.f};

    const char* kbase = (const char*)(khf + (size_t)bh * 32 * 4096);
    const char* vbase = (const char*)(vtf + (size_t)bh * 32 * 4096);
    const int   seg   = w * 1024 + lane * 16;
    const int   wseg  = w * 1024;

    auto dma = [&](int it, int buf) {
        const char* ks = kbase + (size_t)it * 8192;
        const char* vs = vbase + (size_t)it * 8192;
        char* lk = &lds[buf][0];
        char* lv = &lds[buf][8192];
        #pragma unroll
        for (int q = 0; q < 2; q++) {
            __builtin_amdgcn_global_load_lds(
                (gptr_t)(ks + q * 4096 + seg), (sptr_t)(lk + q * 4096 + wseg), 16, 0, 0);
            __builtin_amdgcn_global_load_lds(
                (gptr_t)(vs + q * 4096 + seg), (sptr_t)(lv + q * 4096 + wseg), 16, 0, 0);
        }
    };

    dma(0, 0);

    for (int it = 0; it < 32; it++) {
        const int buf = it & 1;
        __syncthreads();
        if (it + 1 < 32) dma(it + 1, buf ^ 1);

        const char* lk = &lds[buf][0];
        const char* lv = &lds[buf][8192];

        // QK^T: S^T[kv=64][q=32] via 2 mt x 4 kk MFMA 32x32x16
        f32x16 c[2];
        #pragma unroll
        for (int mt = 0; mt < 2; mt++) {
            #pragma unroll
            for (int r = 0; r < 16; r++) c[mt][r] = 0.f;
            #pragma unroll
            for (int kk = 0; kk < 4; kk++) {
                const f16x8 kfr = *(const f16x8*)(
                    lk + (mt * 32 + l5) * 128 + (((kk * 2 + g) ^ x7) * 16));
                c[mt] = __builtin_amdgcn_mfma_f32_32x32x16_f16(
                    kfr, qf[kk], c[mt], 0, 0, 0);
            }
        }

        // exp2 + pack into PV A-frags; f32 row-sum replaces the ones-MFMA
        f16x8 a[4];
        #pragma unroll
        for (int ks = 0; ks < 4; ks++) {
            float e[8];
            #pragma unroll
            for (int j = 0; j < 8; j++) {
                e[j] = EXP2(c[ks >> 1][(ks & 1) * 8 + j]);
                a[ks][j] = (_Float16)e[j];
            }
            lp[ks] += ((e[0] + e[1]) + (e[2] + e[3]))
                    + ((e[4] + e[5]) + (e[6] + e[7]));
        }

        // PV: o[q=32][d=64] via 2 dt x 4 ks MFMA 32x32x16
        #pragma unroll
        for (int dt = 0; dt < 2; dt++)
            #pragma unroll
            for (int ks = 0; ks < 4; ks++) {
                const f16x8 vfr = *(const f16x8*)(
                    lv + (dt * 32 + l5) * 128 + (((ks * 2 + g) ^ x7) * 16));
                o[dt] = __builtin_amdgcn_mfma_f32_32x32x16_f16(
                    a[ks], vfr, o[dt], 0, 0, 0);
            }
    }

    // epilogue: lane's lp covers its g-half of kv for q = l5; xor-32 completes.
    // o C-layout rows q = (r&3)+8*(r>>2)+4g need l[q] -> tiny LDS redistribute.
    float lf = (lp[0] + lp[1]) + (lp[2] + lp[3]);
    lf += __shfl_xor(lf, 32, 64);
    float* lsc = (float*)(void*)&lds[0][0] + w * 64;   // 256B/wave, loop done
    lsc[lane] = 1.f / lf;
    __syncthreads();
    #pragma unroll
    for (int r = 0; r < 16; r++) {
        const int qrow = (r & 3) + 8 * (r >> 2) + 4 * g;
        const float li = lsc[qrow];                     // broadcast read
        float* op = out + ((size_t)b * S_ + q0 + w * 32 + qrow) * HID_
                  + (size_t)h * HD_ + l5;
        op[0]  = o[0][r] * li;
        op[32] = o[1][r] * li;
    }
}

// ---------------------------------------------------------------------------
extern "C" void kernel_launch(void* const* d_in, const int* in_sizes, int n_in,
                              void* d_out, int out_size, void* d_ws, size_t ws_size,
                              hipStream_t stream) {
    const float* x  = (const float*)d_in[0];
    const float* Wq = (const float*)d_in[1];
    const float* bq = (const float*)d_in[2];
    const float* Wk = (const float*)d_in[3];
    const float* bk = (const float*)d_in[4];
    const float* Wv = (const float*)d_in[5];
    const float* bv = (const float*)d_in[6];
    float* out = (float*)d_out;

    _Float16* q  = (_Float16*)d_ws;
    _Float16* k  = q + QSZ_;
    _Float16* vt = k + QSZ_;
    const size_t need = ((size_t)3 * QSZ_ + WTSZ_) * sizeof(_Float16);
    _Float16* wh = (ws_size >= need) ? (vt + QSZ_)
                                     : (_Float16*)d_out;  // consumed before attn writes out

    wconv<<<WTSZ_ / 256, 256, 0, stream>>>(Wq, Wk, Wv, wh);
    qkv_proj<<<768, 256, 0, stream>>>(x, wh, bq, bk, bv, q, k, vt);
    attn<<<768, 256, 0, stream>>>(q, k, vt, out);
}

// Round 2
// 160.164 us; speedup vs baseline: 1.0340x; 1.0340x over previous
//
#include <hip/hip_runtime.h>
#include <hip/hip_bf16.h>

#define B_    4
#define S_    2048
#define HID_  768
#define H_    12
#define DBLK_ 256
#define HD_   64
#define BH_   (B_ * H_)                 // 48
#define QSZ_  (B_ * H_ * S_ * HD_)      // 6291456 elements
#define WTSZ_ (3 * H_ * HD_ * DBLK_)    // 589824 elements

typedef _Float16 f16x4 __attribute__((ext_vector_type(4)));
typedef _Float16 f16x8 __attribute__((ext_vector_type(8)));
typedef float    f32x4 __attribute__((ext_vector_type(4)));
typedef float    f32x16 __attribute__((ext_vector_type(16)));

#if __has_builtin(__builtin_amdgcn_exp2f)
#define EXP2(x) __builtin_amdgcn_exp2f(x)
#else
#define EXP2(x) exp2f(x)
#endif

typedef const void __attribute__((address_space(1)))* gptr_t;
typedef       void __attribute__((address_space(3)))* sptr_t;

// ---------------------------------------------------------------------------
// Kernel 0: W fp32 -> f16 in exact MFMA B-fragment order (unchanged).
// ---------------------------------------------------------------------------
__global__ __launch_bounds__(256) void wconv(
    const float* __restrict__ Wq, const float* __restrict__ Wk,
    const float* __restrict__ Wv, _Float16* __restrict__ whf)
{
    const int idx  = blockIdx.x * 256 + threadIdx.x;
    const int j    = idx & 7;
    const int lane = (idx >> 3) & 63;
    const int et   = (idx >> 9) & 1;
    const int kk   = (idx >> 10) & 7;
    const int eh   = (idx >> 13) & 1;
    const int ph   = idx >> 14;          // p*12 + h
    const int h    = ph % H_;
    const int p    = ph / H_;
    const int e = eh * 32 + et * 16 + (lane & 15);
    const int k = kk * 32 + (lane >> 4) * 8 + j;
    const float* W = (p == 0) ? Wq : (p == 1) ? Wk : Wv;
    whf[idx] = (_Float16)W[((size_t)h * DBLK_ + k) * HD_ + e];
}

// ---------------------------------------------------------------------------
// Kernel 1: block-diagonal QKV projection (unchanged from R1: K rows stored
// with bit2<->bit3 swap so 32x32 swapped-QK C-regs pack directly into PV
// A-frags that contract against V^T columns read linearly).
// ---------------------------------------------------------------------------
__global__ __launch_bounds__(256, 3) void qkv_proj(
    const float* __restrict__ x, const _Float16* __restrict__ whf,
    const float* __restrict__ bq, const float* __restrict__ bk,
    const float* __restrict__ bv,
    _Float16* __restrict__ qo, _Float16* __restrict__ khf,
    _Float16* __restrict__ vtf)
{
    const int i   = blockIdx.x;          // g*128 + sc
    const int g   = i >> 7;              // 0..5
    const int sc  = i & 127;
    const int m   = g >> 1;
    const int s0g = sc * 64;

    const int tid  = threadIdx.x;
    const int lane = tid & 63;
    const int w    = tid >> 6;
    const int ln   = lane & 15;
    const int qd   = lane >> 4;
    const int h    = 2 * g + (w >> 1);
    const int eh   = w & 1;

    __shared__ _Float16 xs[64 * 256];    // 32 KB, reused by the epilogue

    {   // stage X: 64 rows x 256 cols, fp32 -> f16, 16B-granule XOR swizzle
        const int rr   = tid >> 6;
        const int c4   = tid & 63;
        const int g16  = c4 >> 1;
        const int half = c4 & 1;
        #pragma unroll
        for (int pass = 0; pass < 16; pass++) {
            const int r = pass * 4 + rr;
            const float4 v = *(const float4*)(
                x + (size_t)(s0g + r) * HID_ + m * DBLK_ + c4 * 4);
            f16x4 hv;
            hv[0] = (_Float16)v.x; hv[1] = (_Float16)v.y;
            hv[2] = (_Float16)v.z; hv[3] = (_Float16)v.w;
            *(f16x4*)(xs + r * 256 + ((g16 ^ (r & 7)) * 8) + half * 4) = hv;
        }
    }
    __syncthreads();

    f32x4 acc[3][2][4];                  // [p][et][strip]
    #pragma unroll
    for (int p = 0; p < 3; p++)
        #pragma unroll
        for (int et = 0; et < 2; et++)
            #pragma unroll
            for (int st = 0; st < 4; st++)
                acc[p][et][st] = (f32x4){0.f, 0.f, 0.f, 0.f};

    const _Float16* wb = whf + (size_t)((h * 2 + eh) * 16) * 512 + lane * 8;

    for (int kk = 0; kk < 8; kk++) {
        f16x8 a[4];
        #pragma unroll
        for (int st = 0; st < 4; st++)
            a[st] = *(const f16x8*)(
                xs + (st * 16 + ln) * 256 + (((kk * 4 + qd) ^ (ln & 7)) * 8));
        #pragma unroll
        for (int p = 0; p < 3; p++)
            #pragma unroll
            for (int et = 0; et < 2; et++) {
                const f16x8 bb = *(const f16x8*)(
                    wb + (size_t)p * 196608 + (kk * 2 + et) * 512);
                #pragma unroll
                for (int st = 0; st < 4; st++)
                    acc[p][et][st] = __builtin_amdgcn_mfma_f32_16x16x32_f16(
                        a[st], bb, acc[p][et][st], 0, 0, 0);
            }
    }

    const float QS = 0.18033688011112042f;   // 0.125 * log2(e)
    const int b    = s0g >> 11;
    const int s0   = s0g & 2047;
    const int bhh  = b * H_ + h;
    const int tile = s0 >> 6;
    const int ht   = w >> 1;

    __syncthreads();                      // xs MFMA reads done; reuse as Q/K tiles
    // xs layout: Q tiles [ht][64 rows][8 chunks], K tiles at +8192 elems.
    // Both stored with chunk pos = c ^ (row&7). K rows bit2<->bit3 swapped.
    {
        _Float16* qtile = xs + ht * 4096;
        _Float16* ktile = xs + 8192 + ht * 4096;
        const size_t tbv = (size_t)(bhh * 32 + tile) * 4096;
        #pragma unroll
        for (int et = 0; et < 2; et++) {
            const int d  = eh * 32 + et * 16 + ln;
            const int dc = d >> 3, d7 = d & 7;
            const float biasq = bq[h * HD_ + d];
            const float biask = bk[h * HD_ + d];
            const float biasv = bv[h * HD_ + d];
            #pragma unroll
            for (int st = 0; st < 4; st++) {
                // V: direct global store, f16x4, swizzled V^T tile [d][kv]
                f16x4 vv;
                #pragma unroll
                for (int r = 0; r < 4; r++) vv[r] = (_Float16)(acc[2][et][st][r] + biasv);
                const int vc = st * 2 + (qd >> 1);
                *(f16x4*)(vtf + tbv + d * 64 + ((vc ^ d7) * 8) + (qd & 1) * 4) = vv;
                // Q/K into LDS (transpose staging)
                #pragma unroll
                for (int r = 0; r < 4; r++) {
                    const int sl  = st * 16 + qd * 4 + r;
                    // token sl = st*16 + qd*4 + r; row = swap(bit2,bit3)(sl)
                    const int rho = st * 16 + (qd & 1) * 8 + (qd >> 1) * 4 + r;
                    qtile[sl  * 64 + ((dc ^ (sl  & 7)) * 8) + d7] =
                        (_Float16)((acc[0][et][st][r] + biasq) * QS);
                    ktile[rho * 64 + ((dc ^ (rho & 7)) * 8) + d7] =
                        (_Float16)(acc[1][et][st][r] + biask);
                }
            }
        }
    }
    __syncthreads();
    // copy-out: 4 b128 Q + 4 b128 K per thread, fully coalesced global stores
    #pragma unroll
    for (int it = 0; it < 4; it++) {
        const int idx  = it * 256 + tid;      // 0..1023
        const int ht2  = idx >> 9;
        const int rest = idx & 511;
        const int row  = rest >> 3;
        const int c    = rest & 7;
        const int bhh2 = b * H_ + 2 * g + ht2;
        // Q: unswizzle (read pos c^(row&7), write chunk c), natural row order
        const f16x8 qv = *(const f16x8*)(xs + ht2 * 4096 + row * 64 + ((c ^ (row & 7)) * 8));
        *(f16x8*)(qo + ((size_t)bhh2 * S_ + s0 + row) * HD_ + c * 8) = qv;
        // K: swizzle is part of the global tile layout -> linear copy
        const f16x8 kv8 = *(const f16x8*)(xs + 8192 + ht2 * 4096 + row * 64 + c * 8);
        *(f16x8*)(khf + (size_t)(bhh2 * 32 + tile) * 4096 + row * 64 + c * 8) = kv8;
    }
}

// ---------------------------------------------------------------------------
// Kernel 2: flash attention, 32x32x16 MFMA (8 QK + 8 PV per iter), swapped QK.
// R2 fix: ALL 16 ds_read_b128 hoisted to the top of the iteration as array
// inits (old-schedule discipline). R1 spread them through the MFMA loops,
// which overlapped them with the prefetch DMA's LDS write-backs -> 6.29M
// read/write bank collisions. Clustered reads complete (~200cy) before the
// L2-resident DMA returns (~300cy) start landing.
// ---------------------------------------------------------------------------
__global__ __launch_bounds__(256, 3) void attn(
    const _Float16* __restrict__ qh, const _Float16* __restrict__ khf,
    const _Float16* __restrict__ vtf, float* __restrict__ out)
{
    const int i    = blockIdx.x;          // 0..767
    const int slot = i >> 3;
    const int bh   = (i & 7) * 6 + (slot % 6);   // XCD-banded bh
    const int qt   = slot / 6;            // 0..15
    const int h = bh % H_, b = bh / H_;
    const int q0 = qt * 128;

    const int tid  = threadIdx.x;
    const int lane = tid & 63;
    const int w    = tid >> 6;
    const int l5   = lane & 31;           // q-col / kv-row / d-row index
    const int g    = lane >> 5;           // k-slot group
    const int x7   = l5 & 7;              // chunk-XOR key

    __shared__ __align__(16) char lds[2][16384];   // [buf][ K 8KB | V 8KB ]

    // Q B-frags (pre-scaled by 0.125*log2e): lane holds q = l5, k = kk*16+8g+j
    f16x8 qf[4];
    {
        const _Float16* qb = qh + ((size_t)bh * S_ + q0 + w * 32 + l5) * HD_;
        #pragma unroll
        for (int kk = 0; kk < 4; kk++)
            qf[kk] = *(const f16x8*)(qb + kk * 16 + g * 8);
    }

    f32x16 o[2];
    #pragma unroll
    for (int dt = 0; dt < 2; dt++)
        #pragma unroll
        for (int r = 0; r < 16; r++) o[dt][r] = 0.f;
    float lp[4] = {0.f, 0.f, 0.f, 0.f};

    const char* kbase = (const char*)(khf + (size_t)bh * 32 * 4096);
    const char* vbase = (const char*)(vtf + (size_t)bh * 32 * 4096);
    const int   seg   = w * 1024 + lane * 16;
    const int   wseg  = w * 1024;

    auto dma = [&](int it, int buf) {
        const char* ks = kbase + (size_t)it * 8192;
        const char* vs = vbase + (size_t)it * 8192;
        char* lk = &lds[buf][0];
        char* lv = &lds[buf][8192];
        #pragma unroll
        for (int q = 0; q < 2; q++) {
            __builtin_amdgcn_global_load_lds(
                (gptr_t)(ks + q * 4096 + seg), (sptr_t)(lk + q * 4096 + wseg), 16, 0, 0);
            __builtin_amdgcn_global_load_lds(
                (gptr_t)(vs + q * 4096 + seg), (sptr_t)(lv + q * 4096 + wseg), 16, 0, 0);
        }
    };

    dma(0, 0);

    for (int it = 0; it < 32; it++) {
        const int buf = it & 1;
        __syncthreads();
        if (it + 1 < 32) dma(it + 1, buf ^ 1);

        const char* lk = &lds[buf][0];
        const char* lv = &lds[buf][8192];

        // ALL LDS reads upfront (array inits), clustered before DMA returns.
        f16x8 kf[2][4];
        #pragma unroll
        for (int mt = 0; mt < 2; mt++)
            #pragma unroll
            for (int kk = 0; kk < 4; kk++)
                kf[mt][kk] = *(const f16x8*)(
                    lk + (mt * 32 + l5) * 128 + (((kk * 2 + g) ^ x7) * 16));
        f16x8 vf[2][4];
        #pragma unroll
        for (int dt = 0; dt < 2; dt++)
            #pragma unroll
            for (int ks = 0; ks < 4; ks++)
                vf[dt][ks] = *(const f16x8*)(
                    lv + (dt * 32 + l5) * 128 + (((ks * 2 + g) ^ x7) * 16));

        // QK^T: S^T[kv=64][q=32] via 2 mt x 4 kk MFMA 32x32x16
        f32x16 c[2];
        #pragma unroll
        for (int mt = 0; mt < 2; mt++) {
            #pragma unroll
            for (int r = 0; r < 16; r++) c[mt][r] = 0.f;
            #pragma unroll
            for (int kk = 0; kk < 4; kk++)
                c[mt] = __builtin_amdgcn_mfma_f32_32x32x16_f16(
                    kf[mt][kk], qf[kk], c[mt], 0, 0, 0);
        }

        // exp2 + pack into PV A-frags; f32 row-sum replaces the ones-MFMA
        f16x8 a[4];
        #pragma unroll
        for (int ks = 0; ks < 4; ks++) {
            float e[8];
            #pragma unroll
            for (int j = 0; j < 8; j++) {
                e[j] = EXP2(c[ks >> 1][(ks & 1) * 8 + j]);
                a[ks][j] = (_Float16)e[j];
            }
            lp[ks] += ((e[0] + e[1]) + (e[2] + e[3]))
                    + ((e[4] + e[5]) + (e[6] + e[7]));
        }

        // PV: o[q=32][d=64] via 2 dt x 4 ks MFMA 32x32x16
        #pragma unroll
        for (int dt = 0; dt < 2; dt++)
            #pragma unroll
            for (int ks = 0; ks < 4; ks++)
                o[dt] = __builtin_amdgcn_mfma_f32_32x32x16_f16(
                    a[ks], vf[dt][ks], o[dt], 0, 0, 0);
    }

    // epilogue: lane's lp covers its g-half of kv for q = l5; xor-32 completes.
    // o C-layout rows q = (r&3)+8*(r>>2)+4g need l[q] -> tiny LDS redistribute.
    float lf = (lp[0] + lp[1]) + (lp[2] + lp[3]);
    lf += __shfl_xor(lf, 32, 64);
    float* lsc = (float*)(void*)&lds[0][0] + w * 64;   // 256B/wave, loop done
    lsc[lane] = 1.f / lf;
    __syncthreads();
    #pragma unroll
    for (int r = 0; r < 16; r++) {
        const int qrow = (r & 3) + 8 * (r >> 2) + 4 * g;
        const float li = lsc[qrow];                     // broadcast read
        float* op = out + ((size_t)b * S_ + q0 + w * 32 + qrow) * HID_
                  + (size_t)h * HD_ + l5;
        op[0]  = o[0][r] * li;
        op[32] = o[1][r] * li;
    }
}

// ---------------------------------------------------------------------------
extern "C" void kernel_launch(void* const* d_in, const int* in_sizes, int n_in,
                              void* d_out, int out_size, void* d_ws, size_t ws_size,
                              hipStream_t stream) {
    const float* x  = (const float*)d_in[0];
    const float* Wq = (const float*)d_in[1];
    const float* bq = (const float*)d_in[2];
    const float* Wk = (const float*)d_in[3];
    const float* bk = (const float*)d_in[4];
    const float* Wv = (const float*)d_in[5];
    const float* bv = (const float*)d_in[6];
    float* out = (float*)d_out;

    _Float16* q  = (_Float16*)d_ws;
    _Float16* k  = q + QSZ_;
    _Float16* vt = k + QSZ_;
    const size_t need = ((size_t)3 * QSZ_ + WTSZ_) * sizeof(_Float16);
    _Float16* wh = (ws_size >= need) ? (vt + QSZ_)
                                     : (_Float16*)d_out;  // consumed before attn writes out

    wconv<<<WTSZ_ / 256, 256, 0, stream>>>(Wq, Wk, Wv, wh);
    qkv_proj<<<768, 256, 0, stream>>>(x, wh, bq, bk, bv, q, k, vt);
    attn<<<768, 256, 0, stream>>>(q, k, vt, out);
}